// Round 3
// baseline (708.997 us; speedup 1.0000x reference)
//
#include <hip/hip_runtime.h>
#include <cstdint>

#define NB 4
#define NN 4096
#define CAP 128                 // max neighbors kept per row (mean 32, ~12 sigma headroom)
#define BN_ROWS (NB*NN)         // 16384 node rows
#define EPS_C 1e-5f

typedef __attribute__((ext_vector_type(4))) float f32x4;
typedef __attribute__((ext_vector_type(8))) short sv8;

__device__ inline unsigned rne16(float f) {          // f32 -> bf16 bits (RNE)
    unsigned u = __builtin_bit_cast(unsigned, f);
    return (u + 0x7fffu + ((u >> 16) & 1u)) >> 16;
}
__device__ inline float b2f(unsigned h) { return __builtin_bit_cast(float, h << 16); }

// ---------------------------------------------------------------------------
// Mask format detection: bool may arrive as u8(1B), i32(4B), or f32(4B).
// ---------------------------------------------------------------------------
__global__ __launch_bounds__(256) void detect_mask_fmt(const uint8_t* __restrict__ m,
                                                       int* __restrict__ flag) {
    __shared__ int cnt;
    if (threadIdx.x == 0) cnt = 0;
    __syncthreads();
    int c = 0;
    #pragma unroll
    for (int t = 0; t < 16; t++) c += (m[threadIdx.x * 16 + t] != 0) ? 1 : 0;
    atomicAdd(&cnt, c);
    __syncthreads();
    if (threadIdx.x == 0) *flag = (cnt < 1400) ? 0 : ((cnt < 2765) ? 2 : 1);  // 0=i32 2=f32 1=u8
}

__global__ __launch_bounds__(256) void expand_mask(const void* __restrict__ mraw,
                                                   const int* __restrict__ flag,
                                                   float* __restrict__ maskf) {
    int i = blockIdx.x * 256 + threadIdx.x;
    if (i >= BN_ROWS) return;
    int f = *flag;
    bool v;
    if (f == 0)      v = ((const int*)mraw)[i] != 0;
    else if (f == 1) v = ((const uint8_t*)mraw)[i] != 0;
    else             v = ((const float*)mraw)[i] != 0.0f;
    maskf[i] = v ? 1.0f : 0.0f;
}

// ---------------------------------------------------------------------------
// Build neighbor lists (GLOBAL row index = batch*NN + col, fits uint16).
// ---------------------------------------------------------------------------
__global__ __launch_bounds__(256) void build_adj(const float* __restrict__ adj,
                                                 uint16_t* __restrict__ nbr,
                                                 int* __restrict__ counts) {
    int r = blockIdx.x;
    const int gbase = r & ~(NN - 1);
    const float4* row = (const float4*)(adj + (size_t)r * NN);
    __shared__ int cnt;
    if (threadIdx.x == 0) cnt = 0;
    __syncthreads();
    uint16_t* out = nbr + (size_t)r * CAP;
    #pragma unroll
    for (int t = 0; t < 4; t++) {
        int j4 = t * 256 + threadIdx.x;
        float4 f = row[j4];
        if (f.x != 0.0f) { int p = atomicAdd(&cnt, 1); if (p < CAP) out[p] = (uint16_t)(gbase + j4 * 4 + 0); }
        if (f.y != 0.0f) { int p = atomicAdd(&cnt, 1); if (p < CAP) out[p] = (uint16_t)(gbase + j4 * 4 + 1); }
        if (f.z != 0.0f) { int p = atomicAdd(&cnt, 1); if (p < CAP) out[p] = (uint16_t)(gbase + j4 * 4 + 2); }
        if (f.w != 0.0f) { int p = atomicAdd(&cnt, 1); if (p < CAP) out[p] = (uint16_t)(gbase + j4 * 4 + 3); }
    }
    __syncthreads();
    if (threadIdx.x == 0) counts[r] = min(cnt, (int)CAP);
}

// ---------------------------------------------------------------------------
// MFMA GIN layer. 1 wave/block; block handles 16 GEMM rows = 8 nodes.
// rows r = node*2 + k, features CI per row. GEMM1: H^T = Wa^T @ agg^T (M=64
// hidden ch, N=16 rows, K=CI). GEMM2: O^T = Wb^T @ H^T (M=CO, K=64).
// bf16 hi/lo split on both operands, 3-term products -> ~fp32 precision.
// A/B frags use the SAME (group,elem)->k mapping, so the hardware's internal
// k order cancels (K-permutation invariance). C/D layout: col=lane&15,
// row=(lane>>4)*4+reg (m89-verified).
// ---------------------------------------------------------------------------
template<int CI, int CO, bool FOLD>
__global__ __launch_bounds__(64, 2) void gin_layer_mfma(
    const float* __restrict__ xin, float* __restrict__ xout,
    const uint16_t* __restrict__ nbr, const int* __restrict__ counts,
    const float* __restrict__ maskf,
    const float* __restrict__ Wa, const float* __restrict__ ba,
    const float* __restrict__ bng, const float* __restrict__ bnb,
    const float* __restrict__ bnm, const float* __restrict__ bnv,
    const float* __restrict__ Wb, const float* __restrict__ bb,
    const float* __restrict__ og, const float* __restrict__ ob,
    const float* __restrict__ om, const float* __restrict__ ov)
{
    constexpr int F   = 2 * CI;      // flattened feature width per node
    constexpr int AST = CI + 8;      // agg LDS row stride (shorts) — 16B-aligned, bank-spread
    constexpr int HST = 72;          // H LDS row stride (shorts)
    constexpr int KS1 = CI / 32;     // K-steps GEMM1
    constexpr int T2N = CO / 16;     // och tiles GEMM2

    __shared__ short aggHi[16 * AST], aggLo[16 * AST];
    __shared__ short hHi[16 * HST],  hLo[16 * HST];
    __shared__ float baS[64], bscS[64], bshS[64], c1S[64], c0S[64];

    const int lane = threadIdx.x;        // 0..63
    const int g    = lane >> 4;          // lane group 0..3
    const int c16  = lane & 15;

    // ---- per-channel params into LDS
    {
        float sc = bng[lane] * rsqrtf(bnv[lane] + EPS_C);
        baS[lane]  = ba[lane];
        bscS[lane] = sc;
        bshS[lane] = bnb[lane] - bnm[lane] * sc;
        if (lane < CO) {
            float c1, c0;
            if (FOLD) { c1 = og[lane] * rsqrtf(ov[lane] + EPS_C);
                        c0 = bb[lane] * c1 + (ob[lane] - om[lane] * c1); }
            else      { c1 = 1.0f; c0 = bb[lane]; }
            c1S[lane] = c1; c0S[lane] = c0;
        }
    }

    // ---- weight fragments into VGPRs (A = W^T: row=och t*16+c16, k=s*32+g*8+j)
    sv8 waH[4][KS1], waL[4][KS1], wbH[T2N][2], wbL[T2N][2];
    #pragma unroll
    for (int t = 0; t < 4; t++)
        #pragma unroll
        for (int s = 0; s < KS1; s++) {
            sv8 hv, lv;
            #pragma unroll
            for (int j = 0; j < 8; j++) {
                float w = Wa[(size_t)(s * 32 + g * 8 + j) * 64 + (t * 16 + c16)];
                unsigned hh = rne16(w);
                hv[j] = (short)hh;
                lv[j] = (short)rne16(w - b2f(hh));
            }
            waH[t][s] = hv; waL[t][s] = lv;
        }
    #pragma unroll
    for (int t = 0; t < T2N; t++)
        #pragma unroll
        for (int s = 0; s < 2; s++) {
            sv8 hv, lv;
            #pragma unroll
            for (int j = 0; j < 8; j++) {
                float w = Wb[(size_t)(s * 32 + g * 8 + j) * CO + (t * 16 + c16)];
                unsigned hh = rne16(w);
                hv[j] = (short)hh;
                lv[j] = (short)rne16(w - b2f(hh));
            }
            wbH[t][s] = hv; wbL[t][s] = lv;
        }

    // ---- sparse aggregation of 8 nodes -> LDS (bf16 hi/lo)
    for (int nl = 0; nl < 8; nl++) {
        const int node = blockIdx.x * 8 + nl;
        const float* xrow = xin + (size_t)node * F;
        float a0 = xrow[lane];
        float a1 = (F == 128) ? xrow[64 + lane] : 0.0f;
        const int cnt = counts[node];
        const uint16_t* nb = nbr + (size_t)node * CAP;
        int iA = nb[lane];
        int iB = nb[64 + lane];
        for (int j = 0; j < cnt; j++) {
            int jj = __shfl((j < 64) ? iA : iB, j & 63);
            const float* xr = xin + (size_t)jj * F;
            a0 += xr[lane];
            if (F == 128) a1 += xr[64 + lane];
        }
        if (CI == 64) {
            unsigned h0 = rne16(a0), h1 = rne16(a1);
            aggHi[(2 * nl) * AST + lane]     = (short)h0;
            aggLo[(2 * nl) * AST + lane]     = (short)rne16(a0 - b2f(h0));
            aggHi[(2 * nl + 1) * AST + lane] = (short)h1;
            aggLo[(2 * nl + 1) * AST + lane] = (short)rne16(a1 - b2f(h1));
        } else {  // CI==32: lanes 0-31 -> k=0 row, lanes 32-63 -> k=1 row
            int r = 2 * nl + (lane >> 5), cc = lane & 31;
            unsigned h0 = rne16(a0);
            aggHi[r * AST + cc] = (short)h0;
            aggLo[r * AST + cc] = (short)rne16(a0 - b2f(h0));
        }
    }
    __syncthreads();

    // ---- GEMM1: acc1[t] = H^T tile (rows och t*16+4g+q, col c16)
    f32x4 acc1[4] = {};
    #pragma unroll
    for (int s = 0; s < KS1; s++) {
        sv8 bh = *(const sv8*)&aggHi[c16 * AST + s * 32 + g * 8];
        sv8 bl = *(const sv8*)&aggLo[c16 * AST + s * 32 + g * 8];
        #pragma unroll
        for (int t = 0; t < 4; t++) {
            acc1[t] = __builtin_amdgcn_mfma_f32_16x16x32_bf16(waH[t][s], bh, acc1[t], 0, 0, 0);
            acc1[t] = __builtin_amdgcn_mfma_f32_16x16x32_bf16(waH[t][s], bl, acc1[t], 0, 0, 0);
            acc1[t] = __builtin_amdgcn_mfma_f32_16x16x32_bf16(waL[t][s], bh, acc1[t], 0, 0, 0);
        }
    }

    // ---- epilogue1: h = bn(relu(acc + ba)) -> H LDS (row=c16, hch) hi/lo
    #pragma unroll
    for (int t = 0; t < 4; t++)
        #pragma unroll
        for (int qp = 0; qp < 2; qp++) {
            int och0 = t * 16 + g * 4 + qp * 2;
            float2 ba2 = *(const float2*)&baS[och0];
            float2 sc2 = *(const float2*)&bscS[och0];
            float2 sh2 = *(const float2*)&bshS[och0];
            float v0 = fmaxf(acc1[t][qp * 2]     + ba2.x, 0.0f) * sc2.x + sh2.x;
            float v1 = fmaxf(acc1[t][qp * 2 + 1] + ba2.y, 0.0f) * sc2.y + sh2.y;
            unsigned h0 = rne16(v0), h1 = rne16(v1);
            hHi[c16 * HST + och0]     = (short)h0;
            hLo[c16 * HST + och0]     = (short)rne16(v0 - b2f(h0));
            hHi[c16 * HST + och0 + 1] = (short)h1;
            hLo[c16 * HST + och0 + 1] = (short)rne16(v1 - b2f(h1));
        }
    __syncthreads();

    // ---- GEMM2: acc2[t] = O^T tile
    f32x4 acc2[T2N] = {};
    #pragma unroll
    for (int s = 0; s < 2; s++) {
        sv8 bh = *(const sv8*)&hHi[c16 * HST + s * 32 + g * 8];
        sv8 bl = *(const sv8*)&hLo[c16 * HST + s * 32 + g * 8];
        #pragma unroll
        for (int t = 0; t < T2N; t++) {
            acc2[t] = __builtin_amdgcn_mfma_f32_16x16x32_bf16(wbH[t][s], bh, acc2[t], 0, 0, 0);
            acc2[t] = __builtin_amdgcn_mfma_f32_16x16x32_bf16(wbH[t][s], bl, acc2[t], 0, 0, 0);
            acc2[t] = __builtin_amdgcn_mfma_f32_16x16x32_bf16(wbL[t][s], bh, acc2[t], 0, 0, 0);
        }
    }

    // ---- epilogue2: o = acc*c1 + c0, mask, store (64B-sector-aligned x4)
    const int row = blockIdx.x * 16 + c16;
    const float m = maskf[row >> 1];
    #pragma unroll
    for (int t = 0; t < T2N; t++) {
        f32x4 o;
        #pragma unroll
        for (int q = 0; q < 4; q++) {
            int och = t * 16 + g * 4 + q;
            o[q] = (acc2[t][q] * c1S[och] + c0S[och]) * m;
        }
        *(f32x4*)(xout + (size_t)row * CO + t * 16 + g * 4) = o;
    }
}

// ---------------------------------------------------------------------------
extern "C" void kernel_launch(void* const* d_in, const int* in_sizes, int n_in,
                              void* d_out, int out_size, void* d_ws, size_t ws_size,
                              hipStream_t stream) {
    const float* x   = (const float*)d_in[0];
    const float* adj = (const float*)d_in[1];
    const void*  msk = d_in[2];
    const float* P[35];
    for (int i = 0; i < n_in && i < 35; i++) P[i] = (const float*)d_in[i];

    uint8_t* w = (uint8_t*)d_ws;
    size_t off = 0;
    auto take = [&](size_t bytes) -> uint8_t* {
        uint8_t* p = w + off;
        off = (off + bytes + 255) & ~(size_t)255;
        return p;
    };
    int*      flag   = (int*)     take(4);
    float*    maskf  = (float*)   take((size_t)BN_ROWS * 4);
    int*      counts = (int*)     take((size_t)BN_ROWS * 4);
    uint16_t* nbrs   = (uint16_t*)take((size_t)BN_ROWS * CAP * 2);
    float*    xA     = (float*)   take((size_t)BN_ROWS * 128 * 4);
    float*    xB     = (float*)   take((size_t)BN_ROWS * 128 * 4);
    (void)ws_size; (void)in_sizes; (void)out_size;

    hipLaunchKernelGGL(detect_mask_fmt, dim3(1), dim3(256), 0, stream,
                       (const uint8_t*)msk, flag);
    hipLaunchKernelGGL(expand_mask, dim3(BN_ROWS / 256), dim3(256), 0, stream,
                       msk, flag, maskf);
    hipLaunchKernelGGL(build_adj, dim3(BN_ROWS), dim3(256), 0, stream,
                       adj, nbrs, counts);

    const int TILES = (2 * BN_ROWS) / 16;  // 32768 rows / 16 = 2048 blocks

    // layer 0: CI=32 -> CO=64, fold og0/ob0/om0/ov0
    hipLaunchKernelGGL((gin_layer_mfma<32, 64, true>), dim3(TILES), dim3(64), 0, stream,
                       x, xA, nbrs, counts, maskf,
                       P[3], P[4], P[5], P[6], P[7], P[8], P[9], P[10],
                       P[27], P[28], P[29], P[30]);
    // layer 1: CI=64 -> CO=64, fold og1/ob1/om1/ov1
    hipLaunchKernelGGL((gin_layer_mfma<64, 64, true>), dim3(TILES), dim3(64), 0, stream,
                       xA, xB, nbrs, counts, maskf,
                       P[11], P[12], P[13], P[14], P[15], P[16], P[17], P[18],
                       P[31], P[32], P[33], P[34]);
    // layer 2: CI=64 -> CO=32, no fold, write final output
    hipLaunchKernelGGL((gin_layer_mfma<64, 32, false>), dim3(TILES), dim3(64), 0, stream,
                       xB, (float*)d_out, nbrs, counts, maskf,
                       P[19], P[20], P[21], P[22], P[23], P[24], P[25], P[26],
                       P[27], P[28], P[29], P[30]);
}

// Round 4
// 537.896 us; speedup vs baseline: 1.3181x; 1.3181x over previous
//
#include <hip/hip_runtime.h>
#include <cstdint>

#define NB 4
#define NN 4096
#define CAP 128                 // max neighbors kept per row (mean 32, ~12 sigma headroom)
#define BN_ROWS (NB*NN)         // 16384 node rows
#define EPS_C 1e-5f

typedef __attribute__((ext_vector_type(4))) float f32x4;

// ---------------------------------------------------------------------------
// Mask format detection: bool may arrive as u8(1B), i32(4B), or f32(4B).
// ---------------------------------------------------------------------------
__global__ __launch_bounds__(256) void detect_mask_fmt(const uint8_t* __restrict__ m,
                                                       int* __restrict__ flag) {
    __shared__ int cnt;
    if (threadIdx.x == 0) cnt = 0;
    __syncthreads();
    int c = 0;
    #pragma unroll
    for (int t = 0; t < 16; t++) c += (m[threadIdx.x * 16 + t] != 0) ? 1 : 0;
    atomicAdd(&cnt, c);
    __syncthreads();
    if (threadIdx.x == 0) *flag = (cnt < 1400) ? 0 : ((cnt < 2765) ? 2 : 1);  // 0=i32 2=f32 1=u8
}

// ---------------------------------------------------------------------------
// Build neighbor lists (GLOBAL row index = batch*NN + col, fits uint16).
// Mask expansion fused in (thread 0 of block r handles mask[r]).
// ---------------------------------------------------------------------------
__global__ __launch_bounds__(256) void build_adj(const float* __restrict__ adj,
                                                 const void* __restrict__ mraw,
                                                 const int* __restrict__ flag,
                                                 uint16_t* __restrict__ nbr,
                                                 int* __restrict__ counts,
                                                 float* __restrict__ maskf) {
    int r = blockIdx.x;
    const int gbase = r & ~(NN - 1);
    const float4* row = (const float4*)(adj + (size_t)r * NN);
    __shared__ int cnt;
    if (threadIdx.x == 0) {
        cnt = 0;
        int f = *flag; bool v;
        if (f == 0)      v = ((const int*)mraw)[r] != 0;
        else if (f == 1) v = ((const uint8_t*)mraw)[r] != 0;
        else             v = ((const float*)mraw)[r] != 0.0f;
        maskf[r] = v ? 1.0f : 0.0f;
    }
    __syncthreads();
    uint16_t* out = nbr + (size_t)r * CAP;
    #pragma unroll
    for (int t = 0; t < 4; t++) {
        int j4 = t * 256 + threadIdx.x;
        float4 f = row[j4];
        if (f.x != 0.0f) { int p = atomicAdd(&cnt, 1); if (p < CAP) out[p] = (uint16_t)(gbase + j4 * 4 + 0); }
        if (f.y != 0.0f) { int p = atomicAdd(&cnt, 1); if (p < CAP) out[p] = (uint16_t)(gbase + j4 * 4 + 1); }
        if (f.z != 0.0f) { int p = atomicAdd(&cnt, 1); if (p < CAP) out[p] = (uint16_t)(gbase + j4 * 4 + 2); }
        if (f.w != 0.0f) { int p = atomicAdd(&cnt, 1); if (p < CAP) out[p] = (uint16_t)(gbase + j4 * 4 + 3); }
    }
    __syncthreads();
    if (threadIdx.x == 0) counts[r] = min(cnt, (int)CAP);
}

// ---------------------------------------------------------------------------
// Fused GIN layer, v3: wave per node, lane = output channel.
//   - weights in registers (coalesced column loads, fp32, loaded sequentially)
//   - agg/h staged in tiny LDS; GEMV reads them as b128 same-address
//     broadcasts (conflict-free, 4 values per LDS instr)
//   - gather: float2 per lane for F=128 (one load/neighbor), unrolled x4
// Per-wave LDS RAW (write then cross-lane read) is in-order within a wave.
// ---------------------------------------------------------------------------
template<int CI, int CO, bool FOLD>
__global__ __launch_bounds__(256) void gin_layer_v3(
    const float* __restrict__ xin, float* __restrict__ xout,
    const uint16_t* __restrict__ nbr, const int* __restrict__ counts,
    const float* __restrict__ maskf,
    const float* __restrict__ Wa, const float* __restrict__ ba,
    const float* __restrict__ bng, const float* __restrict__ bnb,
    const float* __restrict__ bnm, const float* __restrict__ bnv,
    const float* __restrict__ Wb, const float* __restrict__ bb,
    const float* __restrict__ og, const float* __restrict__ ob,
    const float* __restrict__ om, const float* __restrict__ ov)
{
    constexpr int F = 2 * CI;     // flattened feature width (k-major: f = k*CI+c)
    __shared__ float aggS[4][128];
    __shared__ float hS[4][128];
    const int tid = threadIdx.x, lane = tid & 63, wv = tid >> 6;
    const int node = blockIdx.x * 4 + wv;

    // --- per-lane epilogue params (lane = hidden ch for BN1; co for output)
    const float ba_v = ba[lane];
    const float bsc  = bng[lane] * rsqrtf(bnv[lane] + EPS_C);
    const float bsh  = bnb[lane] - bnm[lane] * bsc;
    const int   co   = (CO == 64) ? lane : (lane & 31);
    float c1 = 1.0f, c0 = bb[co];
    if (FOLD) { c1 = og[co] * rsqrtf(ov[co] + EPS_C); c0 = bb[co] * c1 + ob[co] - om[co] * c1; }
    const float m = maskf[node];

    // --- Wa column into registers (issued early, consumed after gather)
    float wa[CI];
    #pragma unroll
    for (int c = 0; c < CI; c++) wa[c] = Wa[c * 64 + lane];

    // --- sparse aggregation (self + neighbors), unrolled x4
    const int cnt = counts[node];
    const uint16_t* nb = nbr + (size_t)node * CAP;
    int iA = nb[lane];
    int iB = nb[64 + lane];
    if (F == 128) {
        const float2* xr2 = (const float2*)(xin + (size_t)node * 128);
        float2 a = xr2[lane];                       // lane holds f = 2*lane, 2*lane+1
        int j = 0;
        for (; j + 4 <= cnt; j += 4) {
            int j0 = __shfl((j + 0 < 64) ? iA : iB, (j + 0) & 63);
            int j1 = __shfl((j + 1 < 64) ? iA : iB, (j + 1) & 63);
            int j2 = __shfl((j + 2 < 64) ? iA : iB, (j + 2) & 63);
            int j3 = __shfl((j + 3 < 64) ? iA : iB, (j + 3) & 63);
            float2 v0 = ((const float2*)(xin + (size_t)j0 * 128))[lane];
            float2 v1 = ((const float2*)(xin + (size_t)j1 * 128))[lane];
            float2 v2 = ((const float2*)(xin + (size_t)j2 * 128))[lane];
            float2 v3 = ((const float2*)(xin + (size_t)j3 * 128))[lane];
            a.x += v0.x + v1.x + v2.x + v3.x;
            a.y += v0.y + v1.y + v2.y + v3.y;
        }
        for (; j < cnt; j++) {
            int jj = __shfl((j < 64) ? iA : iB, j & 63);
            float2 v = ((const float2*)(xin + (size_t)jj * 128))[lane];
            a.x += v.x; a.y += v.y;
        }
        ((float2*)&aggS[wv][0])[lane] = a;          // f-ordered
    } else {  // F == 64
        const float* xr = xin + (size_t)node * 64;
        float a = xr[lane];
        int j = 0;
        for (; j + 4 <= cnt; j += 4) {
            int j0 = __shfl((j + 0 < 64) ? iA : iB, (j + 0) & 63);
            int j1 = __shfl((j + 1 < 64) ? iA : iB, (j + 1) & 63);
            int j2 = __shfl((j + 2 < 64) ? iA : iB, (j + 2) & 63);
            int j3 = __shfl((j + 3 < 64) ? iA : iB, (j + 3) & 63);
            float v0 = xin[(size_t)j0 * 64 + lane];
            float v1 = xin[(size_t)j1 * 64 + lane];
            float v2 = xin[(size_t)j2 * 64 + lane];
            float v3 = xin[(size_t)j3 * 64 + lane];
            a += v0 + v1 + v2 + v3;
        }
        for (; j < cnt; j++) {
            int jj = __shfl((j < 64) ? iA : iB, j & 63);
            a += xin[(size_t)jj * 64 + lane];
        }
        aggS[wv][lane] = a;
    }

    // --- GEMV1: h[k][lane] = sum_c agg[k*CI+c] * wa[c]   (b128 broadcasts)
    float h0a = ba_v, h0b = 0.0f, h1a = ba_v, h1b = 0.0f;
    #pragma unroll
    for (int c4 = 0; c4 < CI / 4; c4++) {
        f32x4 b0 = *(const f32x4*)&aggS[wv][c4 * 4];
        f32x4 b1 = *(const f32x4*)&aggS[wv][CI + c4 * 4];
        h0a += b0[0] * wa[c4 * 4 + 0]; h0b += b0[1] * wa[c4 * 4 + 1];
        h0a += b0[2] * wa[c4 * 4 + 2]; h0b += b0[3] * wa[c4 * 4 + 3];
        h1a += b1[0] * wa[c4 * 4 + 0]; h1b += b1[1] * wa[c4 * 4 + 1];
        h1a += b1[2] * wa[c4 * 4 + 2]; h1b += b1[3] * wa[c4 * 4 + 3];
    }
    float h0 = fmaxf(h0a + h0b, 0.0f) * bsc + bsh;
    float h1 = fmaxf(h1a + h1b, 0.0f) * bsc + bsh;
    hS[wv][lane]      = h0;
    hS[wv][64 + lane] = h1;

    // --- Wb column into registers (wa now dead; regs reused)
    float wb[64];
    #pragma unroll
    for (int j = 0; j < 64; j++) wb[j] = Wb[j * CO + co];

    // --- GEMV2 + folded BN + mask + store
    if (CO == 64) {
        float o0a = 0.0f, o0b = 0.0f, o1a = 0.0f, o1b = 0.0f;
        #pragma unroll
        for (int j4 = 0; j4 < 16; j4++) {
            f32x4 u0 = *(const f32x4*)&hS[wv][j4 * 4];
            f32x4 u1 = *(const f32x4*)&hS[wv][64 + j4 * 4];
            o0a += u0[0] * wb[j4 * 4 + 0]; o0b += u0[1] * wb[j4 * 4 + 1];
            o0a += u0[2] * wb[j4 * 4 + 2]; o0b += u0[3] * wb[j4 * 4 + 3];
            o1a += u1[0] * wb[j4 * 4 + 0]; o1b += u1[1] * wb[j4 * 4 + 1];
            o1a += u1[2] * wb[j4 * 4 + 2]; o1b += u1[3] * wb[j4 * 4 + 3];
        }
        float o0 = ((o0a + o0b) * c1 + c0) * m;
        float o1 = ((o1a + o1b) * c1 + c0) * m;
        xout[(size_t)node * 128 + lane]      = o0;
        xout[(size_t)node * 128 + 64 + lane] = o1;
    } else {  // CO == 32: lane -> (k = lane>>5, co = lane&31)
        const int k = lane >> 5;
        float oa = 0.0f, ob_ = 0.0f;
        #pragma unroll
        for (int j4 = 0; j4 < 16; j4++) {
            f32x4 u = *(const f32x4*)&hS[wv][k * 64 + j4 * 4];
            oa  += u[0] * wb[j4 * 4 + 0]; ob_ += u[1] * wb[j4 * 4 + 1];
            oa  += u[2] * wb[j4 * 4 + 2]; ob_ += u[3] * wb[j4 * 4 + 3];
        }
        float o = ((oa + ob_) * c1 + c0) * m;
        xout[(size_t)node * 64 + lane] = o;
    }
}

// ---------------------------------------------------------------------------
extern "C" void kernel_launch(void* const* d_in, const int* in_sizes, int n_in,
                              void* d_out, int out_size, void* d_ws, size_t ws_size,
                              hipStream_t stream) {
    const float* x   = (const float*)d_in[0];
    const float* adj = (const float*)d_in[1];
    const void*  msk = d_in[2];
    const float* P[35];
    for (int i = 0; i < n_in && i < 35; i++) P[i] = (const float*)d_in[i];

    uint8_t* w = (uint8_t*)d_ws;
    size_t off = 0;
    auto take = [&](size_t bytes) -> uint8_t* {
        uint8_t* p = w + off;
        off = (off + bytes + 255) & ~(size_t)255;
        return p;
    };
    int*      flag   = (int*)     take(4);
    float*    maskf  = (float*)   take((size_t)BN_ROWS * 4);
    int*      counts = (int*)     take((size_t)BN_ROWS * 4);
    uint16_t* nbrs   = (uint16_t*)take((size_t)BN_ROWS * CAP * 2);
    float*    xA     = (float*)   take((size_t)BN_ROWS * 128 * 4);
    float*    xB     = (float*)   take((size_t)BN_ROWS * 128 * 4);
    (void)ws_size; (void)in_sizes; (void)out_size;

    hipLaunchKernelGGL(detect_mask_fmt, dim3(1), dim3(256), 0, stream,
                       (const uint8_t*)msk, flag);
    hipLaunchKernelGGL(build_adj, dim3(BN_ROWS), dim3(256), 0, stream,
                       adj, msk, flag, nbrs, counts, maskf);

    // layer 0: CI=32 -> CO=64, fold og0/ob0/om0/ov0
    hipLaunchKernelGGL((gin_layer_v3<32, 64, true>), dim3(BN_ROWS / 4), dim3(256), 0, stream,
                       x, xA, nbrs, counts, maskf,
                       P[3], P[4], P[5], P[6], P[7], P[8], P[9], P[10],
                       P[27], P[28], P[29], P[30]);
    // layer 1: CI=64 -> CO=64, fold og1/ob1/om1/ov1
    hipLaunchKernelGGL((gin_layer_v3<64, 64, true>), dim3(BN_ROWS / 4), dim3(256), 0, stream,
                       xA, xB, nbrs, counts, maskf,
                       P[11], P[12], P[13], P[14], P[15], P[16], P[17], P[18],
                       P[31], P[32], P[33], P[34]);
    // layer 2: CI=64 -> CO=32, no fold, write final output
    hipLaunchKernelGGL((gin_layer_v3<64, 32, false>), dim3(BN_ROWS / 4), dim3(256), 0, stream,
                       xB, (float*)d_out, nbrs, counts, maskf,
                       P[19], P[20], P[21], P[22], P[23], P[24], P[25], P[26],
                       P[27], P[28], P[29], P[30]);
}